// Round 5
// baseline (131.109 us; speedup 1.0000x reference)
//
#include <hip/hip_runtime.h>
#include <hip/hip_bf16.h>

// Renderer interpolation: out[p, d] = sum_k bary[p,k] * attributes[faces[wrap(pix[p])][k], d]
// mask[p] = (pix[p] != -1)
// H=W=1024, D=32, F=100000, V=50000.
//
// Strategy (round 5): physical d-major transpose of the attribute table into
// 4 line-contiguous slices of 32B/vertex (1.6MB each) in d_ws, then gather
// each slice only from the XCDs that own it (slice = blockIdx%4; dispatch
// round-robins blockIdx%8 across XCDs). Per-XCD L2 working set becomes
// 1.6MB slice + 1.2MB faces = 2.8MB < 4MB -> gathers hit L2 (34TB/s) instead
// of missing to L3/HBM. Round-4 evidence: without the transpose the per-XCD
// working set in 128B L2 *lines* never shrank (FETCH_SIZE 224MB, 106us).

typedef float fvec4 __attribute__((ext_vector_type(4)));

// ---- pre-pass: attr[V][8 fvec4] -> ws[s][v][j] (s=chunk pair 0..3, j=0..1) ----
__global__ __launch_bounds__(256) void Renderer_transpose_kernel(
    const fvec4* __restrict__ A,   // attr as fvec4[V*8]
    fvec4* __restrict__ W,         // ws as fvec4[4][V][2]
    int V)
{
    int tid = blockIdx.x * blockDim.x + threadIdx.x;
    if (tid >= V * 8) return;
    int v = tid >> 3;
    int c = tid & 7;          // float4 chunk 0..7
    int s = c >> 1;           // slice 0..3
    int j = c & 1;            // half within slice
    W[((size_t)s * V + v) * 2 + j] = A[tid];
}

// ---- main: one slice per block; 2 lanes per pixel; 128 pixels per block ----
__global__ __launch_bounds__(256) void Renderer_interp_sliced_kernel(
    const int* __restrict__ pix,      // (npix)
    const float* __restrict__ bary,   // (npix, 3)
    const int* __restrict__ faces,    // (F, 3)
    const fvec4* __restrict__ W,      // transposed attr: [4][V][2] fvec4
    float* __restrict__ out,          // (npix, 32)
    float* __restrict__ mask,         // (npix) as float 0/1
    int npix, int F, int V)
{
    int s     = blockIdx.x & 3;        // slice (maps to XCD under bid%8 rr)
    int pblk  = blockIdx.x >> 2;       // pixel-group index (128 pixels)
    int lp    = threadIdx.x >> 1;      // local pixel 0..127
    int j     = threadIdx.x & 1;       // which float4 of the 32B slice chunk
    int p     = pblk * 128 + lp;
    if (p >= npix) return;

    // stage 1: pixel->face (stream; cached for the 3 sibling blocks via L3)
    int fraw = pix[p];
    int f = (fraw < 0) ? (fraw + F) : fraw;   // mode='wrap': -1 -> F-1

    // stage 2: face->vertices (1.2MB table, L2-resident per XCD)
    int base = 3 * f;
    int v0 = faces[base + 0];
    int v1 = faces[base + 1];
    int v2 = faces[base + 2];

    float w0 = bary[3 * p + 0];
    float w1 = bary[3 * p + 1];
    float w2 = bary[3 * p + 2];

    // stage 3: vertex->attr slice (1.6MB contiguous, L2-resident per XCD)
    const fvec4* S = W + (size_t)s * V * 2;
    fvec4 r0 = S[v0 * 2 + j];
    fvec4 r1 = S[v1 * 2 + j];
    fvec4 r2 = S[v2 * 2 + j];

    fvec4 o = w0 * r0 + w1 * r1 + w2 * r2;

    // output: 32B per (pixel, slice); partial-line stores merge in L3
    fvec4* O = reinterpret_cast<fvec4*>(out);
    __builtin_nontemporal_store(o, &O[(size_t)p * 8 + s * 2 + j]);

    if (s == 0 && j == 0) {
        __builtin_nontemporal_store((fraw != -1) ? 1.0f : 0.0f, &mask[p]);
    }
}

// ---- fallback (round-1 structure) if ws is too small ----
__global__ __launch_bounds__(256) void Renderer_interp_kernel(
    const int* __restrict__ pix, const float* __restrict__ bary,
    const int* __restrict__ faces, const float* __restrict__ attr,
    float* __restrict__ out, float* __restrict__ mask, int npix, int F)
{
    int tid = blockIdx.x * blockDim.x + threadIdx.x;
    int p = tid >> 3;
    int t = tid & 7;
    if (p >= npix) return;
    int fraw = pix[p];
    int f = (fraw < 0) ? (fraw + F) : fraw;
    int base = 3 * f;
    int v0 = faces[base + 0], v1 = faces[base + 1], v2 = faces[base + 2];
    float w0 = bary[3 * p + 0], w1 = bary[3 * p + 1], w2 = bary[3 * p + 2];
    const fvec4* A = reinterpret_cast<const fvec4*>(attr);
    fvec4 r0 = A[v0 * 8 + t], r1 = A[v1 * 8 + t], r2 = A[v2 * 8 + t];
    fvec4 o = w0 * r0 + w1 * r1 + w2 * r2;
    reinterpret_cast<fvec4*>(out)[(size_t)p * 8 + t] = o;
    if (t == 0) mask[p] = (fraw != -1) ? 1.0f : 0.0f;
}

extern "C" void kernel_launch(void* const* d_in, const int* in_sizes, int n_in,
                              void* d_out, int out_size, void* d_ws, size_t ws_size,
                              hipStream_t stream) {
    const int*   pix   = (const int*)d_in[0];
    const float* bary  = (const float*)d_in[1];
    const int*   faces = (const int*)d_in[2];
    const float* attr  = (const float*)d_in[3];

    int npix = in_sizes[0];        // H*W = 1048576
    int F    = in_sizes[2] / 3;    // 100000
    int V    = in_sizes[3] / 32;   // 50000

    float* out  = (float*)d_out;                      // (npix, 32)
    float* mask = (float*)d_out + (size_t)npix * 32;  // (npix,)

    size_t need = (size_t)V * 32 * sizeof(float);     // 6.4MB transposed table

    if (ws_size >= need) {
        fvec4* W = (fvec4*)d_ws;
        int nthr = V * 8;
        Renderer_transpose_kernel<<<(nthr + 255) / 256, 256, 0, stream>>>(
            (const fvec4*)attr, W, V);
        // 128 pixels per group, 4 slice-blocks per group
        int nblk = ((npix + 127) / 128) * 4;
        Renderer_interp_sliced_kernel<<<nblk, 256, 0, stream>>>(
            pix, bary, faces, W, out, mask, npix, F, V);
    } else {
        int total = npix * 8;
        Renderer_interp_kernel<<<(total + 255) / 256, 256, 0, stream>>>(
            pix, bary, faces, attr, out, mask, npix, F);
    }
}

// Round 6
// 72.317 us; speedup vs baseline: 1.8130x; 1.8130x over previous
//
#include <hip/hip_runtime.h>
#include <hip/hip_bf16.h>

// Renderer interpolation: out[p, d] = sum_k bary[p,k] * attributes[faces[wrap(pix[p])][k], d]
// mask[p] = (pix[p] != -1).  H=W=1024, D=32, F=100000, V=50000.
//
// Round-6 strategy: COMPRESS the gather tables so they fit each XCD's 4MB L2,
// while keeping full-row gather coalescing (round 5 showed slicing rows
// across blocks quadruples line-touches and loses badly).
//   - attributes f32 -> bf16 (RTNE): 6.4MB -> 3.2MB, 64B rows
//   - faces int32 -> uint16 (V=50000 < 2^16): 1.2MB -> 0.6MB
//   working set 3.8MB < 4MB per-XCD L2 -> gathers become L2 hits.
// Main kernel: 4 lanes/pixel, each loads 16B (8 bf16) => one full 64B row per
// pixel group, expands to f32 (exact), f32 math. Streams (pix/bary/out/mask)
// use nontemporal hints to avoid evicting the tables.
// Numerics: bf16 RTNE adds <= ~0.01 abs error (attrs ~N(0,1), weights sum to
// 1); threshold is 8.56e-2, round-1 margin was 7.8e-3.

typedef float fvec4 __attribute__((ext_vector_type(4)));
typedef unsigned short usvec8 __attribute__((ext_vector_type(8)));

__device__ __forceinline__ float bf16_to_f32(unsigned short h) {
    unsigned int u = ((unsigned int)h) << 16;
    return __builtin_bit_cast(float, u);
}

// ---- pre-pass: attr f32->bf16 (RTNE), faces i32->u16 ----
__global__ __launch_bounds__(256) void Renderer_prep_kernel(
    const float* __restrict__ attr, const int* __restrict__ faces,
    unsigned short* __restrict__ attr16, unsigned short* __restrict__ faces16,
    int nattr, int nfidx)
{
    int tid = blockIdx.x * blockDim.x + threadIdx.x;
    if (tid < nattr) {
        unsigned int u = __builtin_bit_cast(unsigned int, attr[tid]);
        unsigned int r = (u + 0x7FFFu + ((u >> 16) & 1u)) >> 16;   // RTNE
        attr16[tid] = (unsigned short)r;
    } else if (tid < nattr + nfidx) {
        int i = tid - nattr;
        faces16[i] = (unsigned short)faces[i];
    }
}

// ---- main: 4 lanes per pixel, 16B bf16 gather per lane (full 64B row/pixel) ----
__global__ __launch_bounds__(256) void Renderer_interp16_kernel(
    const int* __restrict__ pix,              // (npix)
    const float* __restrict__ bary,           // (npix, 3)
    const unsigned short* __restrict__ faces16, // (F, 3) u16
    const usvec8* __restrict__ A,             // attr16 as (V*4) 16B chunks
    float* __restrict__ out,                  // (npix, 32)
    float* __restrict__ mask,                 // (npix) as float 0/1
    int npix, int F)
{
    int tid = blockIdx.x * blockDim.x + threadIdx.x;
    int p = tid >> 2;          // pixel
    int t = tid & 3;           // 8-element chunk of the 32-d row
    if (p >= npix) return;

    int fraw = __builtin_nontemporal_load(&pix[p]);
    int f = (fraw < 0) ? (fraw + F) : fraw;   // mode='wrap': -1 -> F-1

    int b = 3 * f;
    int v0 = faces16[b + 0];
    int v1 = faces16[b + 1];
    int v2 = faces16[b + 2];

    float w0 = __builtin_nontemporal_load(&bary[3 * p + 0]);
    float w1 = __builtin_nontemporal_load(&bary[3 * p + 1]);
    float w2 = __builtin_nontemporal_load(&bary[3 * p + 2]);

    usvec8 r0 = A[v0 * 4 + t];
    usvec8 r1 = A[v1 * 4 + t];
    usvec8 r2 = A[v2 * 4 + t];

    fvec4 lo, hi;
    #pragma unroll
    for (int j = 0; j < 4; ++j) {
        float x = w0 * bf16_to_f32(r0[j]) + w1 * bf16_to_f32(r1[j])
                + w2 * bf16_to_f32(r2[j]);
        lo[j] = x;
    }
    #pragma unroll
    for (int j = 0; j < 4; ++j) {
        float x = w0 * bf16_to_f32(r0[j + 4]) + w1 * bf16_to_f32(r1[j + 4])
                + w2 * bf16_to_f32(r2[j + 4]);
        hi[j] = x;
    }

    fvec4* O = reinterpret_cast<fvec4*>(out);
    __builtin_nontemporal_store(lo, &O[(size_t)p * 8 + t * 2 + 0]);
    __builtin_nontemporal_store(hi, &O[(size_t)p * 8 + t * 2 + 1]);

    if (t == 0) {
        __builtin_nontemporal_store((fraw != -1) ? 1.0f : 0.0f, &mask[p]);
    }
}

// ---- fallback (round-1 structure) if ws too small ----
__global__ __launch_bounds__(256) void Renderer_interp_kernel(
    const int* __restrict__ pix, const float* __restrict__ bary,
    const int* __restrict__ faces, const float* __restrict__ attr,
    float* __restrict__ out, float* __restrict__ mask, int npix, int F)
{
    int tid = blockIdx.x * blockDim.x + threadIdx.x;
    int p = tid >> 3;
    int t = tid & 7;
    if (p >= npix) return;
    int fraw = pix[p];
    int f = (fraw < 0) ? (fraw + F) : fraw;
    int base = 3 * f;
    int v0 = faces[base + 0], v1 = faces[base + 1], v2 = faces[base + 2];
    float w0 = bary[3 * p + 0], w1 = bary[3 * p + 1], w2 = bary[3 * p + 2];
    const fvec4* A = reinterpret_cast<const fvec4*>(attr);
    fvec4 r0 = A[v0 * 8 + t], r1 = A[v1 * 8 + t], r2 = A[v2 * 8 + t];
    fvec4 o = w0 * r0 + w1 * r1 + w2 * r2;
    reinterpret_cast<fvec4*>(out)[(size_t)p * 8 + t] = o;
    if (t == 0) mask[p] = (fraw != -1) ? 1.0f : 0.0f;
}

extern "C" void kernel_launch(void* const* d_in, const int* in_sizes, int n_in,
                              void* d_out, int out_size, void* d_ws, size_t ws_size,
                              hipStream_t stream) {
    const int*   pix   = (const int*)d_in[0];
    const float* bary  = (const float*)d_in[1];
    const int*   faces = (const int*)d_in[2];
    const float* attr  = (const float*)d_in[3];

    int npix  = in_sizes[0];        // H*W = 1048576
    int nfidx = in_sizes[2];        // F*3 = 300000
    int nattr = in_sizes[3];        // V*32 = 1600000
    int F     = nfidx / 3;

    float* out  = (float*)d_out;                      // (npix, 32)
    float* mask = (float*)d_out + (size_t)npix * 32;  // (npix,)

    size_t attr16_bytes = (size_t)nattr * sizeof(unsigned short); // 3.2MB
    size_t need = attr16_bytes + (size_t)nfidx * sizeof(unsigned short);

    if (ws_size >= need) {
        unsigned short* attr16  = (unsigned short*)d_ws;
        unsigned short* faces16 = (unsigned short*)((char*)d_ws + attr16_bytes);

        int nprep = nattr + nfidx;
        Renderer_prep_kernel<<<(nprep + 255) / 256, 256, 0, stream>>>(
            attr, faces, attr16, faces16, nattr, nfidx);

        int total = npix * 4;
        Renderer_interp16_kernel<<<(total + 255) / 256, 256, 0, stream>>>(
            pix, bary, faces16, (const usvec8*)attr16, out, mask, npix, F);
    } else {
        int total = npix * 8;
        Renderer_interp_kernel<<<(total + 255) / 256, 256, 0, stream>>>(
            pix, bary, faces, attr, out, mask, npix, F);
    }
}

// Round 7
// 71.053 us; speedup vs baseline: 1.8452x; 1.0178x over previous
//
#include <hip/hip_runtime.h>
#include <hip/hip_bf16.h>

// Renderer interpolation: out[p, d] = sum_k bary[p,k] * attributes[faces[wrap(pix[p])][k], d]
// mask[p] = (pix[p] != -1).  H=W=1024, D=32, F=100000, V=50000.
//
// Round-7: split the gather working set across two passes so each pass's hot
// table fits per-XCD L2 (4MB) with headroom under stream flow-through —
// the regime round 5 PROVED achieves residency (FETCH 224->46MB):
//   prep : attr f32 -> bf16 rows (3.2MB table)
//   passA: pix -> faces gather (hot: faces 1.2MB), emit packed u16x4
//          (v0,v1,v2,flag) to ws + mask
//   passB: attr16 gather ONLY (hot: 3.2MB, resident), interpolate, store.
// Full-row coalescing preserved: 4 lanes/pixel x 16B = one 64B bf16 row.

typedef float fvec4 __attribute__((ext_vector_type(4)));
typedef unsigned short usvec8 __attribute__((ext_vector_type(8)));
typedef unsigned short usvec4 __attribute__((ext_vector_type(4)));

__device__ __forceinline__ float bf16_to_f32(unsigned short h) {
    unsigned int u = ((unsigned int)h) << 16;
    return __builtin_bit_cast(float, u);
}

// ---- prep: attr f32 -> bf16 (RTNE) ----
__global__ __launch_bounds__(256) void Renderer_prep_kernel(
    const float* __restrict__ attr, unsigned short* __restrict__ attr16,
    int nattr)
{
    int tid = blockIdx.x * blockDim.x + threadIdx.x;
    if (tid >= nattr) return;
    unsigned int u = __builtin_bit_cast(unsigned int, attr[tid]);
    unsigned int r = (u + 0x7FFFu + ((u >> 16) & 1u)) >> 16;   // RTNE
    attr16[tid] = (unsigned short)r;
}

// ---- pass A: pixel -> (v0,v1,v2,flag) packed; hot table = faces (1.2MB) ----
__global__ __launch_bounds__(256) void Renderer_passA_kernel(
    const int* __restrict__ pix,      // (npix)
    const int* __restrict__ faces,    // (F,3)
    usvec4* __restrict__ vtx,         // (npix) packed u16x4
    float* __restrict__ mask,         // (npix)
    int npix, int F)
{
    int p = blockIdx.x * blockDim.x + threadIdx.x;
    if (p >= npix) return;

    int fraw = __builtin_nontemporal_load(&pix[p]);
    int f = (fraw < 0) ? (fraw + F) : fraw;   // mode='wrap': -1 -> F-1

    int b = 3 * f;
    int v0 = faces[b + 0];
    int v1 = faces[b + 1];
    int v2 = faces[b + 2];

    usvec4 pk;
    pk[0] = (unsigned short)v0;
    pk[1] = (unsigned short)v1;
    pk[2] = (unsigned short)v2;
    pk[3] = 0;
    __builtin_nontemporal_store(pk, &vtx[p]);
    __builtin_nontemporal_store((fraw != -1) ? 1.0f : 0.0f, &mask[p]);
}

// ---- pass B: attr16 gather + interpolate; hot table = attr16 (3.2MB) ----
__global__ __launch_bounds__(256) void Renderer_passB_kernel(
    const usvec4* __restrict__ vtx,   // (npix) packed u16x4
    const float* __restrict__ bary,   // (npix,3)
    const usvec8* __restrict__ A,     // attr16 as (V*4) 16B chunks
    float* __restrict__ out,          // (npix,32)
    int npix)
{
    int tid = blockIdx.x * blockDim.x + threadIdx.x;
    int p = tid >> 2;          // pixel
    int t = tid & 3;           // 8-elem chunk of the 32-d row
    if (p >= npix) return;

    usvec4 pk = __builtin_nontemporal_load(&vtx[p]);
    int v0 = pk[0], v1 = pk[1], v2 = pk[2];

    float w0 = __builtin_nontemporal_load(&bary[3 * p + 0]);
    float w1 = __builtin_nontemporal_load(&bary[3 * p + 1]);
    float w2 = __builtin_nontemporal_load(&bary[3 * p + 2]);

    usvec8 r0 = A[v0 * 4 + t];
    usvec8 r1 = A[v1 * 4 + t];
    usvec8 r2 = A[v2 * 4 + t];

    fvec4 lo, hi;
    #pragma unroll
    for (int j = 0; j < 4; ++j) {
        lo[j] = w0 * bf16_to_f32(r0[j]) + w1 * bf16_to_f32(r1[j])
              + w2 * bf16_to_f32(r2[j]);
        hi[j] = w0 * bf16_to_f32(r0[j + 4]) + w1 * bf16_to_f32(r1[j + 4])
              + w2 * bf16_to_f32(r2[j + 4]);
    }

    fvec4* O = reinterpret_cast<fvec4*>(out);
    __builtin_nontemporal_store(lo, &O[(size_t)p * 8 + t * 2 + 0]);
    __builtin_nontemporal_store(hi, &O[(size_t)p * 8 + t * 2 + 1]);
}

// ---- fallback (round-1 structure) if ws too small ----
__global__ __launch_bounds__(256) void Renderer_interp_kernel(
    const int* __restrict__ pix, const float* __restrict__ bary,
    const int* __restrict__ faces, const float* __restrict__ attr,
    float* __restrict__ out, float* __restrict__ mask, int npix, int F)
{
    int tid = blockIdx.x * blockDim.x + threadIdx.x;
    int p = tid >> 3;
    int t = tid & 7;
    if (p >= npix) return;
    int fraw = pix[p];
    int f = (fraw < 0) ? (fraw + F) : fraw;
    int base = 3 * f;
    int v0 = faces[base + 0], v1 = faces[base + 1], v2 = faces[base + 2];
    float w0 = bary[3 * p + 0], w1 = bary[3 * p + 1], w2 = bary[3 * p + 2];
    const fvec4* A = reinterpret_cast<const fvec4*>(attr);
    fvec4 r0 = A[v0 * 8 + t], r1 = A[v1 * 8 + t], r2 = A[v2 * 8 + t];
    fvec4 o = w0 * r0 + w1 * r1 + w2 * r2;
    reinterpret_cast<fvec4*>(out)[(size_t)p * 8 + t] = o;
    if (t == 0) mask[p] = (fraw != -1) ? 1.0f : 0.0f;
}

extern "C" void kernel_launch(void* const* d_in, const int* in_sizes, int n_in,
                              void* d_out, int out_size, void* d_ws, size_t ws_size,
                              hipStream_t stream) {
    const int*   pix   = (const int*)d_in[0];
    const float* bary  = (const float*)d_in[1];
    const int*   faces = (const int*)d_in[2];
    const float* attr  = (const float*)d_in[3];

    int npix  = in_sizes[0];        // 1048576
    int nfidx = in_sizes[2];        // 300000
    int nattr = in_sizes[3];        // 1600000
    int F     = nfidx / 3;

    float* out  = (float*)d_out;                      // (npix,32)
    float* mask = (float*)d_out + (size_t)npix * 32;  // (npix,)

    size_t attr16_bytes = (size_t)nattr * sizeof(unsigned short);     // 3.2MB
    size_t vtx_bytes    = (size_t)npix * sizeof(unsigned short) * 4;  // 8MB
    size_t need = attr16_bytes + vtx_bytes;

    if (ws_size >= need) {
        unsigned short* attr16 = (unsigned short*)d_ws;
        usvec4* vtx = (usvec4*)((char*)d_ws + attr16_bytes);

        Renderer_prep_kernel<<<(nattr + 255) / 256, 256, 0, stream>>>(
            attr, attr16, nattr);
        Renderer_passA_kernel<<<(npix + 255) / 256, 256, 0, stream>>>(
            pix, faces, vtx, mask, npix, F);
        int total = npix * 4;
        Renderer_passB_kernel<<<(total + 255) / 256, 256, 0, stream>>>(
            vtx, bary, (const usvec8*)attr16, out, npix);
    } else {
        int total = npix * 8;
        Renderer_interp_kernel<<<(total + 255) / 256, 256, 0, stream>>>(
            pix, bary, faces, attr, out, mask, npix, F);
    }
}

// Round 8
// 65.537 us; speedup vs baseline: 2.0005x; 1.0842x over previous
//
#include <hip/hip_runtime.h>
#include <hip/hip_bf16.h>

// Renderer interpolation: out[p, d] = sum_k bary[p,k] * attributes[faces[wrap(pix[p])][k], d]
// mask[p] = (pix[p] != -1).  H=W=1024, D=32, F=100000, V=50000.
//
// Round-8: EXACT round-1 structure (best so far, 65.6us) with ONE change:
// the three attribute-row gathers bypass the CU L1 via sc0 (device-coherent)
// loads. Theory: r1/r4/r5 fit a per-CU L1-miss-concurrency model (~32 MSHRs
// x ~200cy L2 latency => ~6cy per distinct-line touch); bypassing L1 sends
// gather requests to the much deeper L2 queues, lifting the concurrency cap.
// Line-touch count is unchanged (TA merges the 8 same-line lanes per pixel).
// All three loads are issued in ONE asm block with a single vmcnt(0); the
// results are asm outputs so all later uses are dataflow-ordered (rule #18).

typedef float fvec4 __attribute__((ext_vector_type(4)));

__global__ __launch_bounds__(256) void Renderer_interp_kernel(
    const int* __restrict__ pix,      // (npix)
    const float* __restrict__ bary,   // (npix, 3)
    const int* __restrict__ faces,    // (F, 3)
    const float* __restrict__ attr,   // (V, 32)
    float* __restrict__ out,          // (npix, 32)
    float* __restrict__ mask,         // (npix) as float 0/1
    int npix, int F)
{
    int tid = blockIdx.x * blockDim.x + threadIdx.x;
    int p = tid >> 3;      // pixel index
    int t = tid & 7;       // d-chunk index: handles d = 4t .. 4t+3
    if (p >= npix) return;

    int fraw = pix[p];
    int f = (fraw < 0) ? (fraw + F) : fraw;   // mode='wrap': -1 -> F-1

    int base = 3 * f;
    int v0 = faces[base + 0];
    int v1 = faces[base + 1];
    int v2 = faces[base + 2];

    float w0 = bary[3 * p + 0];
    float w1 = bary[3 * p + 1];
    float w2 = bary[3 * p + 2];

    const fvec4* A = reinterpret_cast<const fvec4*>(attr);
    const fvec4* a0 = A + ((size_t)v0 * 8 + t);
    const fvec4* a1 = A + ((size_t)v1 * 8 + t);
    const fvec4* a2 = A + ((size_t)v2 * 8 + t);

    fvec4 r0, r1, r2;
    asm volatile(
        "global_load_dwordx4 %0, %3, off sc0\n\t"
        "global_load_dwordx4 %1, %4, off sc0\n\t"
        "global_load_dwordx4 %2, %5, off sc0\n\t"
        "s_waitcnt vmcnt(0)"
        : "=&v"(r0), "=&v"(r1), "=&v"(r2)
        : "v"(a0), "v"(a1), "v"(a2)
        : "memory");

    fvec4 o = w0 * r0 + w1 * r1 + w2 * r2;

    reinterpret_cast<fvec4*>(out)[(size_t)p * 8 + t] = o;

    if (t == 0) {
        mask[p] = (fraw != -1) ? 1.0f : 0.0f;
    }
}

extern "C" void kernel_launch(void* const* d_in, const int* in_sizes, int n_in,
                              void* d_out, int out_size, void* d_ws, size_t ws_size,
                              hipStream_t stream) {
    const int*   pix   = (const int*)d_in[0];
    const float* bary  = (const float*)d_in[1];
    const int*   faces = (const int*)d_in[2];
    const float* attr  = (const float*)d_in[3];

    int npix = in_sizes[0];        // H*W = 1048576
    int F    = in_sizes[2] / 3;    // 100000

    float* out  = (float*)d_out;                      // (npix, 32)
    float* mask = (float*)d_out + (size_t)npix * 32;  // (npix,)

    int total = npix * 8;
    int block = 256;
    int grid = (total + block - 1) / block;
    Renderer_interp_kernel<<<grid, block, 0, stream>>>(pix, bary, faces, attr,
                                                       out, mask, npix, F);
}